// Round 6
// baseline (28511.798 us; speedup 1.0000x reference)
//
#include <hip/hip_runtime.h>

#define NB 256
#define NT 512
#define TT 1024
#define HH 512
#define BATCH 256

using v8s   = __attribute__((ext_vector_type(8))) short;
using f32x4 = __attribute__((ext_vector_type(4))) float;

// ---- LDS layout (bytes) ----
// Staging-time: 4 dense panels at 0..131071 (hoisted to VGPRs before t-loop).
// Loop-time: that region is reused as the exchange scratch.
#define O_RZ2I 0        // 32768: Wih2 r|z  bf16 hi+lo [s16][plane2][lane64][16B]
#define O_RZ2H 32768    // 32768: Whh2 r|z
#define O_NA   65536    // 32768: [Wih2_n(8) | Whh1_n(8)]
#define O_RZ1  98304    // 32768: Whh1 r|z
#define O_NB   131072   // 16384: Whh2_n 8 cols compact [s16][plane2][slot32][16B]
#define O_WOUT 147456   // 2048:  Wout col hi+lo [s16][g4][16B]
#define O_ZERO 149504   // 16
#define O_SCR  0        // 16384: exchange, 4 tiles [tile4][rt4][row16][col16] f32
#define O_SCRO 16384    // 256:   ao col exchange [rt4][row16] f32
#define LDS_BYTES 162064

__device__ __forceinline__ float sigf(float v)   { return 1.f / (1.f + __expf(-v)); }
__device__ __forceinline__ float tanhf_(float v) { return 2.f / (1.f + __expf(-2.f * v)) - 1.f; }

__device__ __forceinline__ unsigned short bf16_rne(float f) {
    union { float f; unsigned u; } a; a.f = f;
    unsigned r = (a.u + 0x7fffu + ((a.u >> 16) & 1u)) >> 16;
    return (unsigned short)r;
}
__device__ __forceinline__ float bf16_f(unsigned short h) {
    union { unsigned u; float f; } a; a.u = ((unsigned)h) << 16; return a.f;
}
__device__ __forceinline__ f32x4 MF(v8s a, v8s b, f32x4 c) {
    return __builtin_amdgcn_mfma_f32_16x16x32_bf16(a, b, c, 0, 0, 0);
}

// write-through (LLC) stores for cross-XCD h state; consumers invalidate
// L1/L2 via the acquire fence in gridbar, then read CACHED (L2-shared).
#define GST2(addr, val) \
    asm volatile("global_store_short %0, %1, off sc0 sc1" \
                 :: "v"(addr), "v"(val) : "memory");

// Per-bg hierarchical barrier (8 subcounters x 8 blocks -> group -> flag).
// Producer side: sc0/sc1 stores drained by vmcnt(0) before arrival.
// Consumer side: agent-acquire fence (L1+L2 invalidate) after the flag,
// so subsequent NORMAL loads see fresh data via LLC (r2-validated pattern).
#define BSTR 512
__device__ __forceinline__ void gridbar(unsigned* barr, int bg, int ug, int tid, unsigned ep) {
    asm volatile("s_waitcnt vmcnt(0)" ::: "memory");
    __syncthreads();
    if (tid == 0) {
        unsigned* sub = barr + bg * BSTR + (ug >> 3) * 32;
        unsigned* grp = barr + bg * BSTR + 256;
        unsigned* flg = barr + bg * BSTR + 288;
        unsigned old = __hip_atomic_fetch_add(sub, 1u, __ATOMIC_RELAXED, __HIP_MEMORY_SCOPE_AGENT);
        if (old + 1 == ep * 8u) {
            unsigned g = __hip_atomic_fetch_add(grp, 1u, __ATOMIC_RELAXED, __HIP_MEMORY_SCOPE_AGENT);
            if (g + 1 == ep * 8u)
                __hip_atomic_store(flg, ep, __ATOMIC_RELAXED, __HIP_MEMORY_SCOPE_AGENT);
        }
        while (__hip_atomic_load(flg, __ATOMIC_RELAXED, __HIP_MEMORY_SCOPE_AGENT) < ep)
            __builtin_amdgcn_s_sleep(2);
        __builtin_amdgcn_fence(__ATOMIC_ACQUIRE, "agent");
    }
    __syncthreads();
}

// x: [B][T] -> xT: [T][B]
__global__ __launch_bounds__(256) void k_transpose(const float* __restrict__ x,
                                                   float* __restrict__ xT) {
    __shared__ float tile[64][65];
    const int bt = blockIdx.x, bb = blockIdx.y;
    const int lt = threadIdx.x & 63, lb = threadIdx.x >> 6;
    #pragma unroll 4
    for (int i = 0; i < 16; ++i) {
        int row = lb + i * 4;
        tile[row][lt] = x[(size_t)(bb * 64 + row) * TT + bt * 64 + lt];
    }
    __syncthreads();
    #pragma unroll 4
    for (int i = 0; i < 16; ++i) {
        int row = lb + i * 4;
        xT[(size_t)(bt * 64 + row) * BATCH + bb * 64 + lt] = tile[lt][row];
    }
}

__global__ __launch_bounds__(NT, 1) void gru_mfma(
    const float* __restrict__ xT,
    const float* __restrict__ Wih1, const float* __restrict__ Whh1,
    const float* __restrict__ bih1, const float* __restrict__ bhh1,
    const float* __restrict__ Wih2, const float* __restrict__ Whh2,
    const float* __restrict__ bih2, const float* __restrict__ bhh2,
    const float* __restrict__ Wout, const float* __restrict__ bout,
    float* __restrict__ out,
    unsigned short* __restrict__ hws,
    unsigned* __restrict__ barr)
{
    extern __shared__ char lds_b[];
    const int tid = threadIdx.x, blk = blockIdx.x;
    const int bg = blk >> 6, ug = blk & 63;
    const int u0 = ug * 8;

    // h planes [b][k] bf16 hi/lo, ping-pong
    unsigned short* h1hP[2] = { hws,          hws + 131072 };
    unsigned short* h1lP[2] = { hws + 262144, hws + 393216 };
    unsigned short* h2hP[2] = { hws + 524288, hws + 655360 };
    unsigned short* h2lP[2] = { hws + 786432, hws + 917504 };

    // ================= weight staging (bf16 hi+lo) =================
    for (int i = tid; i < 16 * 512; i += NT) {  // Wih2 r|z
        int n = i >> 9, k = i & 511;
        int row = (n < 8) ? (u0 + n) : (HH + u0 + (n - 8));
        float f = Wih2[(size_t)row * HH + k];
        unsigned short hi = bf16_rne(f), lo = bf16_rne(f - bf16_f(hi));
        int s = k >> 5, g = (k >> 3) & 3, j = k & 7, ln = g * 16 + n;
        int base = O_RZ2I + s * 2048 + ln * 16 + j * 2;
        *(unsigned short*)(lds_b + base) = hi;
        *(unsigned short*)(lds_b + base + 1024) = lo;
    }
    for (int i = tid; i < 16 * 512; i += NT) {  // Whh2 r|z
        int n = i >> 9, k = i & 511;
        int row = (n < 8) ? (u0 + n) : (HH + u0 + (n - 8));
        float f = Whh2[(size_t)row * HH + k];
        unsigned short hi = bf16_rne(f), lo = bf16_rne(f - bf16_f(hi));
        int s = k >> 5, g = (k >> 3) & 3, j = k & 7, ln = g * 16 + n;
        int base = O_RZ2H + s * 2048 + ln * 16 + j * 2;
        *(unsigned short*)(lds_b + base) = hi;
        *(unsigned short*)(lds_b + base + 1024) = lo;
    }
    for (int i = tid; i < 16 * 512; i += NT) {  // [Wih2_n | Whh1_n]
        int n = i >> 9, k = i & 511;
        float f = (n < 8) ? Wih2[(size_t)(2 * HH + u0 + n) * HH + k]
                          : Whh1[(size_t)(2 * HH + u0 + (n - 8)) * HH + k];
        unsigned short hi = bf16_rne(f), lo = bf16_rne(f - bf16_f(hi));
        int s = k >> 5, g = (k >> 3) & 3, j = k & 7, ln = g * 16 + n;
        int base = O_NA + s * 2048 + ln * 16 + j * 2;
        *(unsigned short*)(lds_b + base) = hi;
        *(unsigned short*)(lds_b + base + 1024) = lo;
    }
    for (int i = tid; i < 16 * 512; i += NT) {  // Whh1 r|z
        int n = i >> 9, k = i & 511;
        int row = (n < 8) ? (u0 + n) : (HH + u0 + (n - 8));
        float f = Whh1[(size_t)row * HH + k];
        unsigned short hi = bf16_rne(f), lo = bf16_rne(f - bf16_f(hi));
        int s = k >> 5, g = (k >> 3) & 3, j = k & 7, ln = g * 16 + n;
        int base = O_RZ1 + s * 2048 + ln * 16 + j * 2;
        *(unsigned short*)(lds_b + base) = hi;
        *(unsigned short*)(lds_b + base + 1024) = lo;
    }
    for (int i = tid; i < 8 * 512; i += NT) {   // Whh2_n compact 8 cols
        int c = i >> 9, k = i & 511;
        float f = Whh2[(size_t)(2 * HH + u0 + c) * HH + k];
        unsigned short hi = bf16_rne(f), lo = bf16_rne(f - bf16_f(hi));
        int s = k >> 5, g = (k >> 3) & 3, j = k & 7;
        int base = O_NB + s * 1024 + (g * 8 + c) * 16 + j * 2;
        *(unsigned short*)(lds_b + base) = hi;
        *(unsigned short*)(lds_b + base + 512) = lo;
    }
    for (int k = tid; k < 512; k += NT) {       // Wout col
        float f = Wout[k];
        unsigned short hi = bf16_rne(f), lo = bf16_rne(f - bf16_f(hi));
        int s = k >> 5, g = (k >> 3) & 3, j = k & 7;
        int base = O_WOUT + s * 64 + g * 16 + j * 2;
        *(unsigned short*)(lds_b + base) = hi;
        *(unsigned short*)(lds_b + base + 1024) = lo;
    }
    if (tid < 4) ((unsigned*)(lds_b + O_ZERO))[tid] = 0;

    // ================= h prologue: h2(-1)=0, h1(0)=GRU(x0, 0) =================
    {
        const int rl = tid >> 3, uo = tid & 7;
        const int b = bg * 64 + rl, u = u0 + uo;
        GST2(h2hP[1] + (size_t)b * HH + u, 0u);
        GST2(h2lP[1] + (size_t)b * HH + u, 0u);
        float x0 = xT[b];
        float r = sigf(x0 * Wih1[u] + bih1[u] + bhh1[u]);
        float z = sigf(x0 * Wih1[HH + u] + bih1[HH + u] + bhh1[HH + u]);
        float n = tanhf_(x0 * Wih1[2 * HH + u] + bih1[2 * HH + u] + r * bhh1[2 * HH + u]);
        float h = (1.f - z) * n;
        unsigned short hi = bf16_rne(h), lo = bf16_rne(h - bf16_f(hi));
        GST2(h1hP[0] + (size_t)b * HH + u, (unsigned)hi);
        GST2(h1lP[0] + (size_t)b * HH + u, (unsigned)lo);
    }

    // ================= per-wave/lane constants =================
    const int w = tid >> 6, lane = tid & 63;
    const int n16 = lane & 15, g4 = lane >> 4;
    const int rt = w & 3, kh = w >> 2;       // row-tile(16 rows), k-half(256)
    const int c = n16, cu = c & 7;
    const int u = u0 + cu;
    const int sbase = kh * 8;

    float b2rz = 0, wx1 = 0, b1rz = 0, bin2_ = 0, bhn2_ = 0, wxn1 = 0, bin1_ = 0, bhn1_ = 0;
    float hprev[4] = {0.f, 0.f, 0.f, 0.f};
    if (kh == 1) {
        b2rz = (c < 8) ? bih2[u] + bhh2[u] : bih2[HH + u] + bhh2[HH + u];
        wx1  = (c < 8) ? Wih1[u] : Wih1[HH + u];
        b1rz = (c < 8) ? bih1[u] + bhh1[u] : bih1[HH + u] + bhh1[HH + u];
        bin2_ = bih2[2 * HH + u]; bhn2_ = bhh2[2 * HH + u];
        wxn1 = Wih1[2 * HH + u]; bin1_ = bih1[2 * HH + u]; bhn1_ = bhh1[2 * HH + u];
        if (c >= 8) {  // layer-1 lanes carry h1 in regs: init to h1(0)
            #pragma unroll
            for (int j = 0; j < 4; ++j) {
                int b = bg * 64 + rt * 16 + g4 * 4 + j;
                float x0 = xT[b];
                float r = sigf(x0 * Wih1[u] + bih1[u] + bhh1[u]);
                float z = sigf(x0 * Wih1[HH + u] + bih1[HH + u] + bhh1[HH + u]);
                float nn = tanhf_(x0 * Wih1[2 * HH + u] + bih1[2 * HH + u] + r * bhh1[2 * HH + u]);
                hprev[j] = (1.f - z) * nn;
            }
        }
    }
    const float boutv = bout[0];

    // LDS pointers for the panels that STAY in LDS
    const char* BBh = (n16 < 8) ? lds_b + O_NB + kh * 8192 + (g4 * 8 + n16) * 16
                                : lds_b + O_ZERO;
    const char* BBl = (n16 < 8) ? BBh + 512 : lds_b + O_ZERO;
    const int  bbs  = (n16 < 8) ? 1024 : 0;
    const char* Bo  = (n16 == 0) ? lds_b + O_WOUT + kh * 512 + g4 * 16 : lds_b + O_ZERO;
    const char* Bol = (n16 == 0) ? Bo + 1024 : lds_b + O_ZERO;
    const int  bos  = (n16 == 0) ? 64 : 0;

    float* scr = (float*)(lds_b + O_SCR);   // 4 tiles [tile][rt][row16][col16]
    float* so  = (float*)(lds_b + O_SCRO);

    unsigned ep = 1;
    gridbar(barr, bg, ug, tid, ep);

    // ================= hoist the 4 dense B panels into VGPRs =================
    v8s RBi[8][2], RBh[8][2], RBA[8][2], RB1[8][2];
    {
        const char* Bi = lds_b + O_RZ2I + lane * 16;
        const char* Bh = lds_b + O_RZ2H + lane * 16;
        const char* BA = lds_b + O_NA   + lane * 16;
        const char* B1 = lds_b + O_RZ1  + lane * 16;
        #pragma unroll
        for (int s8 = 0; s8 < 8; ++s8) {
            const int s = sbase + s8;
            RBi[s8][0] = *(const v8s*)(Bi + s * 2048); RBi[s8][1] = *(const v8s*)(Bi + s * 2048 + 1024);
            RBh[s8][0] = *(const v8s*)(Bh + s * 2048); RBh[s8][1] = *(const v8s*)(Bh + s * 2048 + 1024);
            RBA[s8][0] = *(const v8s*)(BA + s * 2048); RBA[s8][1] = *(const v8s*)(BA + s * 2048 + 1024);
            RB1[s8][0] = *(const v8s*)(B1 + s * 2048); RB1[s8][1] = *(const v8s*)(B1 + s * 2048 + 1024);
        }
    }
    __syncthreads();  // panel LDS is dead; scr (same bytes) becomes live

    // ================= main recurrence =================
    for (int t = 0; t <= TT; ++t) {
        const unsigned short* __restrict__ h1rh = h1hP[t & 1];        // h1(t)
        const unsigned short* __restrict__ h1rl = h1lP[t & 1];
        const unsigned short* __restrict__ h2rh = h2hP[(t + 1) & 1];  // h2(t-1)
        const unsigned short* __restrict__ h2rl = h2lP[(t + 1) & 1];
        unsigned short* h2wh = h2hP[t & 1];              // h2(t)
        unsigned short* h2wl = h2lP[t & 1];
        unsigned short* h1wh = h1hP[(t + 1) & 1];        // h1(t+1)
        unsigned short* h1wl = h1lP[(t + 1) & 1];

        const size_t aoff = ((size_t)(bg * 64 + rt * 16 + n16) * HH + (size_t)kh * 256 + g4 * 8);
        const unsigned short* __restrict__ pa1h = h1rh + aoff;
        const unsigned short* __restrict__ pa1l = h1rl + aoff;
        const unsigned short* __restrict__ pa2h = h2rh + aoff;
        const unsigned short* __restrict__ pa2l = h2rl + aoff;

        f32x4 ai = {0.f,0.f,0.f,0.f}, ah = {0.f,0.f,0.f,0.f}, a1v = {0.f,0.f,0.f,0.f};
        f32x4 aA = {0.f,0.f,0.f,0.f}, aB = {0.f,0.f,0.f,0.f}, ao = {0.f,0.f,0.f,0.f};

        #pragma unroll
        for (int sl = 0; sl < 8; ++sl) {
            const v8s a1h = *(const v8s*)(pa1h + sl * 32);
            const v8s a1l = *(const v8s*)(pa1l + sl * 32);
            const v8s a2h = *(const v8s*)(pa2h + sl * 32);
            const v8s a2l = *(const v8s*)(pa2l + sl * 32);
            ai  = MF(a1h, RBi[sl][0], ai);  ai  = MF(a1l, RBi[sl][0], ai);  ai  = MF(a1h, RBi[sl][1], ai);
            ah  = MF(a2h, RBh[sl][0], ah);  ah  = MF(a2l, RBh[sl][0], ah);  ah  = MF(a2h, RBh[sl][1], ah);
            aA  = MF(a1h, RBA[sl][0], aA);  aA  = MF(a1l, RBA[sl][0], aA);  aA  = MF(a1h, RBA[sl][1], aA);
            a1v = MF(a1h, RB1[sl][0], a1v); a1v = MF(a1l, RB1[sl][0], a1v); a1v = MF(a1h, RB1[sl][1], a1v);
            v8s bh = *(const v8s*)(BBh + sl * bbs), bl = *(const v8s*)(BBl + sl * bbs);
            aB = MF(a2h, bh, aB); aB = MF(a2l, bh, aB); aB = MF(a2h, bl, aB);
            bh = *(const v8s*)(Bo + sl * bos); bl = *(const v8s*)(Bol + sl * bos);
            ao = MF(a2h, bh, ao); ao = MF(a2l, bh, ao); ao = MF(a2h, bl, ao);
        }

        // -------- single exchange phase: kh0 publishes 4 tiles + ao col --------
        if (kh == 0) {
            #pragma unroll
            for (int j = 0; j < 4; ++j) {
                const int row = g4 * 4 + j;
                scr[(0 * 4 + rt) * 256 + row * 16 + c] = ai[j] + ah[j];
                scr[(1 * 4 + rt) * 256 + row * 16 + c] = a1v[j];
                scr[(2 * 4 + rt) * 256 + row * 16 + c] = aA[j];
                scr[(3 * 4 + rt) * 256 + row * 16 + c] = aB[j];
            }
            if (c == 0) {
                #pragma unroll
                for (int j = 0; j < 4; ++j) so[rt * 16 + g4 * 4 + j] = ao[j];
            }
        }
        __syncthreads();

        if (kh == 1) {
            float s2v[4], zz2[4], s1v[4], rr1[4], AAv[4], ABv[4], xvv[4];
            #pragma unroll
            for (int j = 0; j < 4; ++j) {
                const int row = g4 * 4 + j;
                const int b = bg * 64 + rt * 16 + row;
                const float AIAH = ai[j] + ah[j] + scr[(0 * 4 + rt) * 256 + row * 16 + c];
                const float A1v  = a1v[j] + scr[(1 * 4 + rt) * 256 + row * 16 + c];
                AAv[j] = aA[j] + scr[(2 * 4 + rt) * 256 + row * 16 + c];
                ABv[j] = aB[j] + scr[(3 * 4 + rt) * 256 + row * 16 + c];
                xvv[j] = (t + 1 < TT) ? xT[(size_t)(t + 1) * BATCH + b] : 0.f;
                s2v[j] = sigf(AIAH + b2rz);                 // r2 (c<8) / z2 (c>=8)
                s1v[j] = sigf(xvv[j] * wx1 + b1rz + A1v);   // r1 (c<8) / z1 (c>=8)
            }
            #pragma unroll
            for (int j = 0; j < 4; ++j) {
                zz2[j] = __shfl_xor(s2v[j], 8);
                rr1[j] = __shfl_xor(s1v[j], 8);
            }
            #pragma unroll
            for (int j = 0; j < 4; ++j) {
                const int row = g4 * 4 + j;
                const int b = bg * 64 + rt * 16 + row;
                if (c < 8) {
                    if (t < TT) {
                        float n2 = tanhf_(AAv[j] + bin2_ + s2v[j] * (ABv[j] + bhn2_));
                        float hn = (1.f - zz2[j]) * n2 + zz2[j] * hprev[j];
                        hprev[j] = hn;
                        unsigned short hi = bf16_rne(hn), lo = bf16_rne(hn - bf16_f(hi));
                        GST2(h2wh + (size_t)b * HH + u, (unsigned)hi);
                        GST2(h2wl + (size_t)b * HH + u, (unsigned)lo);
                    }
                } else {
                    if (t + 1 < TT) {
                        float n1 = tanhf_(xvv[j] * wxn1 + bin1_ + rr1[j] * (AAv[j] + bhn1_));
                        float hn = (1.f - s1v[j]) * n1 + s1v[j] * hprev[j];
                        hprev[j] = hn;
                        unsigned short hi = bf16_rne(hn), lo = bf16_rne(hn - bf16_f(hi));
                        GST2(h1wh + (size_t)b * HH + u, (unsigned)hi);
                        GST2(h1wl + (size_t)b * HH + u, (unsigned)lo);
                    }
                }
                if (c == 0 && ug == 0 && t >= 1) {
                    float AO = ao[j] + so[rt * 16 + row];
                    out[(size_t)b * TT + (t - 1)] = AO + boutv;
                }
            }
        }
        ++ep;
        gridbar(barr, bg, ug, tid, ep);
    }
}

extern "C" void kernel_launch(void* const* d_in, const int* in_sizes, int n_in,
                              void* d_out, int out_size, void* d_ws, size_t ws_size,
                              hipStream_t stream) {
    const float* x    = (const float*)d_in[0];
    const float* Wih1 = (const float*)d_in[1];
    const float* Whh1 = (const float*)d_in[2];
    const float* bih1 = (const float*)d_in[3];
    const float* bhh1 = (const float*)d_in[4];
    const float* Wih2 = (const float*)d_in[5];
    const float* Whh2 = (const float*)d_in[6];
    const float* bih2 = (const float*)d_in[7];
    const float* bhh2 = (const float*)d_in[8];
    const float* Wout = (const float*)d_in[9];
    const float* bout = (const float*)d_in[10];
    float* outp = (float*)d_out;

    unsigned short* hws = (unsigned short*)d_ws;                 // 8 bf16 planes, 2 MB
    float* xT      = (float*)((char*)d_ws + 2097152);            // 1 MB
    unsigned* barr = (unsigned*)((char*)d_ws + 3145728);         // 8 KB

    hipMemsetAsync((void*)barr, 0, 8192, stream);
    k_transpose<<<dim3(16, 4), 256, 0, stream>>>(x, xT);

    hipFuncSetAttribute((const void*)gru_mfma,
                        hipFuncAttributeMaxDynamicSharedMemorySize, LDS_BYTES);

    void* args[] = { (void*)&xT,
                     (void*)&Wih1, (void*)&Whh1, (void*)&bih1, (void*)&bhh1,
                     (void*)&Wih2, (void*)&Whh2, (void*)&bih2, (void*)&bhh2,
                     (void*)&Wout, (void*)&bout,
                     (void*)&outp, (void*)&hws, (void*)&barr };
    hipLaunchCooperativeKernel((void*)gru_mfma, dim3(NB), dim3(NT),
                               args, LDS_BYTES, stream);
}

// Round 7
// 11440.749 us; speedup vs baseline: 2.4921x; 2.4921x over previous
//
#include <hip/hip_runtime.h>

#define NB 256
#define NT 512
#define TT 1024
#define HH 512
#define BATCH 256

using v8s   = __attribute__((ext_vector_type(8))) short;
using f32x4 = __attribute__((ext_vector_type(4))) float;

// ---- LDS layout (bytes) ---- (identical to round-5, proven)
#define O_RZ2I 0        // 32768: Wih2 r|z  bf16 hi+lo [s16][plane2][lane64][16B]
#define O_RZ2H 32768    // 32768: Whh2 r|z
#define O_NA   65536    // 32768: [Wih2_n(8) | Whh1_n(8)]
#define O_RZ1  98304    // 32768: Whh1 r|z
#define O_NB   131072   // 16384: Whh2_n 8 cols compact [s16][plane2][slot32][16B]
#define O_WOUT 147456   // 2048:  Wout col hi+lo [s16][g4][16B]
#define O_ZERO 149504   // 16
#define O_SCR  149520   // 12288: exchange, 3 tiles [tile3][rt4][row16][col16] f32
#define O_SCRO 161808   // 256:   ao col exchange [rt4][row16] f32
#define LDS_BYTES 162064

#define SLOT_SH 524288  // shorts per ring slot: [h1h|h1l|h2h|h2l] x 131072

__device__ __forceinline__ float sigf(float v)   { return 1.f / (1.f + __expf(-v)); }
__device__ __forceinline__ float tanhf_(float v) { return 2.f / (1.f + __expf(-2.f * v)) - 1.f; }

__device__ __forceinline__ unsigned short bf16_rne(float f) {
    union { float f; unsigned u; } a; a.f = f;
    unsigned r = (a.u + 0x7fffu + ((a.u >> 16) & 1u)) >> 16;
    return (unsigned short)r;
}
__device__ __forceinline__ float bf16_f(unsigned short h) {
    union { unsigned u; float f; } a; a.u = ((unsigned)h) << 16; return a.f;
}
__device__ __forceinline__ f32x4 MF(v8s a, v8s b, f32x4 c) {
    return __builtin_amdgcn_mfma_f32_16x16x32_bf16(a, b, c, 0, 0, 0);
}

// write-through stores: h state reaches the chip coherence point (MALL)
// before the barrier's vmcnt(0) drain + flag publish.
#define GST2(addr, val) \
    asm volatile("global_store_short %0, %1, off sc0 sc1" \
                 :: "v"(addr), "v"(val) : "memory");

// Per-bg hierarchical barrier (8 subcounters x 8 blocks -> group -> flag).
// Producer side: sc0/sc1 stores drained by vmcnt(0) before arrival.
// Consumer side: loads are NORMAL (L2-shared). Stale-line hazard is handled
// by the never-reuse ring + a periodic (not per-step!) acquire fence.
#define BSTR 512
__device__ __forceinline__ void gridbar(unsigned* barr, int bg, int ug, int tid,
                                        unsigned ep, bool fence) {
    asm volatile("s_waitcnt vmcnt(0)" ::: "memory");
    __syncthreads();
    if (tid == 0) {
        unsigned* sub = barr + bg * BSTR + (ug >> 3) * 32;
        unsigned* grp = barr + bg * BSTR + 256;
        unsigned* flg = barr + bg * BSTR + 288;
        unsigned old = __hip_atomic_fetch_add(sub, 1u, __ATOMIC_RELAXED, __HIP_MEMORY_SCOPE_AGENT);
        if (old + 1 == ep * 8u) {
            unsigned g = __hip_atomic_fetch_add(grp, 1u, __ATOMIC_RELAXED, __HIP_MEMORY_SCOPE_AGENT);
            if (g + 1 == ep * 8u)
                __hip_atomic_store(flg, ep, __ATOMIC_RELAXED, __HIP_MEMORY_SCOPE_AGENT);
        }
        while (__hip_atomic_load(flg, __ATOMIC_RELAXED, __HIP_MEMORY_SCOPE_AGENT) < ep)
            __builtin_amdgcn_s_sleep(2);
        if (fence)
            __builtin_amdgcn_fence(__ATOMIC_ACQUIRE, "agent");
    }
    __syncthreads();
}

// x: [B][T] -> xT: [T][B]
__global__ __launch_bounds__(256) void k_transpose(const float* __restrict__ x,
                                                   float* __restrict__ xT) {
    __shared__ float tile[64][65];
    const int bt = blockIdx.x, bb = blockIdx.y;
    const int lt = threadIdx.x & 63, lb = threadIdx.x >> 6;
    #pragma unroll 4
    for (int i = 0; i < 16; ++i) {
        int row = lb + i * 4;
        tile[row][lt] = x[(size_t)(bb * 64 + row) * TT + bt * 64 + lt];
    }
    __syncthreads();
    #pragma unroll 4
    for (int i = 0; i < 16; ++i) {
        int row = lb + i * 4;
        xT[(size_t)(bt * 64 + row) * BATCH + bb * 64 + lt] = tile[lt][row];
    }
}

__global__ __launch_bounds__(NT, 1) void gru_mfma(
    const float* __restrict__ xT,
    const float* __restrict__ Wih1, const float* __restrict__ Whh1,
    const float* __restrict__ bih1, const float* __restrict__ bhh1,
    const float* __restrict__ Wih2, const float* __restrict__ Whh2,
    const float* __restrict__ bih2, const float* __restrict__ bhh2,
    const float* __restrict__ Wout, const float* __restrict__ bout,
    float* __restrict__ out,
    unsigned short* __restrict__ hws,
    unsigned* __restrict__ barr,
    int rmask, int invmask)
{
    extern __shared__ char lds_b[];
    const int tid = threadIdx.x, blk = blockIdx.x;
    const int bg = blk >> 6, ug = blk & 63;
    const int u0 = ug * 8;

    // ================= weight staging (bf16 hi+lo) — identical to r5 =========
    for (int i = tid; i < 16 * 512; i += NT) {  // Wih2 r|z
        int n = i >> 9, k = i & 511;
        int row = (n < 8) ? (u0 + n) : (HH + u0 + (n - 8));
        float f = Wih2[(size_t)row * HH + k];
        unsigned short hi = bf16_rne(f), lo = bf16_rne(f - bf16_f(hi));
        int s = k >> 5, g = (k >> 3) & 3, j = k & 7, ln = g * 16 + n;
        int base = O_RZ2I + s * 2048 + ln * 16 + j * 2;
        *(unsigned short*)(lds_b + base) = hi;
        *(unsigned short*)(lds_b + base + 1024) = lo;
    }
    for (int i = tid; i < 16 * 512; i += NT) {  // Whh2 r|z
        int n = i >> 9, k = i & 511;
        int row = (n < 8) ? (u0 + n) : (HH + u0 + (n - 8));
        float f = Whh2[(size_t)row * HH + k];
        unsigned short hi = bf16_rne(f), lo = bf16_rne(f - bf16_f(hi));
        int s = k >> 5, g = (k >> 3) & 3, j = k & 7, ln = g * 16 + n;
        int base = O_RZ2H + s * 2048 + ln * 16 + j * 2;
        *(unsigned short*)(lds_b + base) = hi;
        *(unsigned short*)(lds_b + base + 1024) = lo;
    }
    for (int i = tid; i < 16 * 512; i += NT) {  // [Wih2_n | Whh1_n]
        int n = i >> 9, k = i & 511;
        float f = (n < 8) ? Wih2[(size_t)(2 * HH + u0 + n) * HH + k]
                          : Whh1[(size_t)(2 * HH + u0 + (n - 8)) * HH + k];
        unsigned short hi = bf16_rne(f), lo = bf16_rne(f - bf16_f(hi));
        int s = k >> 5, g = (k >> 3) & 3, j = k & 7, ln = g * 16 + n;
        int base = O_NA + s * 2048 + ln * 16 + j * 2;
        *(unsigned short*)(lds_b + base) = hi;
        *(unsigned short*)(lds_b + base + 1024) = lo;
    }
    for (int i = tid; i < 16 * 512; i += NT) {  // Whh1 r|z
        int n = i >> 9, k = i & 511;
        int row = (n < 8) ? (u0 + n) : (HH + u0 + (n - 8));
        float f = Whh1[(size_t)row * HH + k];
        unsigned short hi = bf16_rne(f), lo = bf16_rne(f - bf16_f(hi));
        int s = k >> 5, g = (k >> 3) & 3, j = k & 7, ln = g * 16 + n;
        int base = O_RZ1 + s * 2048 + ln * 16 + j * 2;
        *(unsigned short*)(lds_b + base) = hi;
        *(unsigned short*)(lds_b + base + 1024) = lo;
    }
    for (int i = tid; i < 8 * 512; i += NT) {   // Whh2_n compact 8 cols
        int c = i >> 9, k = i & 511;
        float f = Whh2[(size_t)(2 * HH + u0 + c) * HH + k];
        unsigned short hi = bf16_rne(f), lo = bf16_rne(f - bf16_f(hi));
        int s = k >> 5, g = (k >> 3) & 3, j = k & 7;
        int base = O_NB + s * 1024 + (g * 8 + c) * 16 + j * 2;
        *(unsigned short*)(lds_b + base) = hi;
        *(unsigned short*)(lds_b + base + 512) = lo;
    }
    for (int k = tid; k < 512; k += NT) {       // Wout col
        float f = Wout[k];
        unsigned short hi = bf16_rne(f), lo = bf16_rne(f - bf16_f(hi));
        int s = k >> 5, g = (k >> 3) & 3, j = k & 7;
        int base = O_WOUT + s * 64 + g * 16 + j * 2;
        *(unsigned short*)(lds_b + base) = hi;
        *(unsigned short*)(lds_b + base + 1024) = lo;
    }
    if (tid < 4) ((unsigned*)(lds_b + O_ZERO))[tid] = 0;

    // ====== h prologue into ring slot 0: h1(0), h2(-1)=0 (write-through) =====
    {
        const int rl = tid >> 3, uo = tid & 7;
        const int b = bg * 64 + rl, u = u0 + uo;
        unsigned short* s0 = hws;  // slot 0
        GST2(s0 + 262144 + (size_t)b * HH + u, 0u);   // h2 hi
        GST2(s0 + 393216 + (size_t)b * HH + u, 0u);   // h2 lo
        float x0 = xT[b];
        float r = sigf(x0 * Wih1[u] + bih1[u] + bhh1[u]);
        float z = sigf(x0 * Wih1[HH + u] + bih1[HH + u] + bhh1[HH + u]);
        float n = tanhf_(x0 * Wih1[2 * HH + u] + bih1[2 * HH + u] + r * bhh1[2 * HH + u]);
        float h = (1.f - z) * n;
        unsigned short hi = bf16_rne(h), lo = bf16_rne(h - bf16_f(hi));
        GST2(s0 + (size_t)b * HH + u, (unsigned)hi);           // h1 hi
        GST2(s0 + 131072 + (size_t)b * HH + u, (unsigned)lo);  // h1 lo
    }

    // ================= per-wave/lane constants (identical to r5) =============
    const int w = tid >> 6, lane = tid & 63;
    const int n16 = lane & 15, g4 = lane >> 4;
    const int rt = w & 3, kh = w >> 2;       // row-tile(16 rows), k-half(256)
    const int c = n16, cu = c & 7;
    const int u = u0 + cu;
    const int sbase = kh * 8;

    float b2rz = 0, wx1 = 0, b1rz = 0, bin2_ = 0, bhn2_ = 0, wxn1 = 0, bin1_ = 0, bhn1_ = 0;
    float hprev[4] = {0.f, 0.f, 0.f, 0.f};
    if (kh == 1) {
        b2rz = (c < 8) ? bih2[u] + bhh2[u] : bih2[HH + u] + bhh2[HH + u];
        wx1  = (c < 8) ? Wih1[u] : Wih1[HH + u];
        b1rz = (c < 8) ? bih1[u] + bhh1[u] : bih1[HH + u] + bhh1[HH + u];
        bin2_ = bih2[2 * HH + u]; bhn2_ = bhh2[2 * HH + u];
        wxn1 = Wih1[2 * HH + u]; bin1_ = bih1[2 * HH + u]; bhn1_ = bhh1[2 * HH + u];
        if (c >= 8) {  // layer-1 lanes carry h1 in regs: init to h1(0)
            #pragma unroll
            for (int j = 0; j < 4; ++j) {
                int b = bg * 64 + rt * 16 + g4 * 4 + j;
                float x0 = xT[b];
                float r = sigf(x0 * Wih1[u] + bih1[u] + bhh1[u]);
                float z = sigf(x0 * Wih1[HH + u] + bih1[HH + u] + bhh1[HH + u]);
                float nn = tanhf_(x0 * Wih1[2 * HH + u] + bih1[2 * HH + u] + r * bhh1[2 * HH + u]);
                hprev[j] = (1.f - z) * nn;
            }
        }
    }
    const float boutv = bout[0];

    // B read pointers (r5-verified, incl. kh offsets on compact panels)
    const char* Bi = lds_b + O_RZ2I + lane * 16;
    const char* Bh = lds_b + O_RZ2H + lane * 16;
    const char* BA = lds_b + O_NA   + lane * 16;
    const char* B1 = lds_b + O_RZ1  + lane * 16;
    const char* BBh = (n16 < 8) ? lds_b + O_NB + kh * 8192 + (g4 * 8 + n16) * 16
                                : lds_b + O_ZERO;
    const char* BBl = (n16 < 8) ? BBh + 512 : lds_b + O_ZERO;
    const int  bbs  = (n16 < 8) ? 1024 : 0;
    const char* Bo  = (n16 == 0) ? lds_b + O_WOUT + kh * 512 + g4 * 16 : lds_b + O_ZERO;
    const char* Bol = (n16 == 0) ? Bo + 1024 : lds_b + O_ZERO;
    const int  bos  = (n16 == 0) ? 64 : 0;

    float* scr = (float*)(lds_b + O_SCR);   // 3 tiles [tile][rt][row16][col16]
    float* so  = (float*)(lds_b + O_SCRO);

    unsigned ep = 1;
    gridbar(barr, bg, ug, tid, ep, false);

    // ================= main recurrence =================
    for (int t = 0; t <= TT; ++t) {
        // ring slots: slot[t] holds {h1(t), h2(t-1)}; write {h1(t+1), h2(t)} to slot[t+1]
        const unsigned short* __restrict__ slotR = hws + (size_t)(t & rmask) * SLOT_SH;
        unsigned short* __restrict__ slotW = hws + (size_t)((t + 1) & rmask) * SLOT_SH;
        const unsigned short* __restrict__ h1rh = slotR;
        const unsigned short* __restrict__ h1rl = slotR + 131072;
        const unsigned short* __restrict__ h2rh = slotR + 262144;
        const unsigned short* __restrict__ h2rl = slotR + 393216;
        unsigned short* h1wh = slotW;
        unsigned short* h1wl = slotW + 131072;
        unsigned short* h2wh = slotW + 262144;
        unsigned short* h2wl = slotW + 393216;

        const size_t aoff = ((size_t)(bg * 64 + rt * 16 + n16) * HH + (size_t)kh * 256 + g4 * 8);
        const unsigned short* __restrict__ pa1h = h1rh + aoff;
        const unsigned short* __restrict__ pa1l = h1rl + aoff;
        const unsigned short* __restrict__ pa2h = h2rh + aoff;
        const unsigned short* __restrict__ pa2l = h2rl + aoff;

        f32x4 ai = {0.f,0.f,0.f,0.f}, ah = {0.f,0.f,0.f,0.f}, a1v = {0.f,0.f,0.f,0.f};
        f32x4 aA = {0.f,0.f,0.f,0.f}, aB = {0.f,0.f,0.f,0.f}, ao = {0.f,0.f,0.f,0.f};

        #pragma unroll
        for (int sl = 0; sl < 8; ++sl) {
            const int s = sbase + sl;
            const v8s a1h = *(const v8s*)(pa1h + sl * 32);  // normal cached loads:
            const v8s a1l = *(const v8s*)(pa1l + sl * 32);  // L2-shared across the
            const v8s a2h = *(const v8s*)(pa2h + sl * 32);  // 8 same-bg blocks/XCD
            const v8s a2l = *(const v8s*)(pa2l + sl * 32);
            v8s bh, bl;
            bh = *(const v8s*)(Bi + s * 2048); bl = *(const v8s*)(Bi + s * 2048 + 1024);
            ai = MF(a1h, bh, ai); ai = MF(a1l, bh, ai); ai = MF(a1h, bl, ai);
            bh = *(const v8s*)(Bh + s * 2048); bl = *(const v8s*)(Bh + s * 2048 + 1024);
            ah = MF(a2h, bh, ah); ah = MF(a2l, bh, ah); ah = MF(a2h, bl, ah);
            bh = *(const v8s*)(BA + s * 2048); bl = *(const v8s*)(BA + s * 2048 + 1024);
            aA = MF(a1h, bh, aA); aA = MF(a1l, bh, aA); aA = MF(a1h, bl, aA);
            bh = *(const v8s*)(B1 + s * 2048); bl = *(const v8s*)(B1 + s * 2048 + 1024);
            a1v = MF(a1h, bh, a1v); a1v = MF(a1l, bh, a1v); a1v = MF(a1h, bl, a1v);
            bh = *(const v8s*)(BBh + sl * bbs); bl = *(const v8s*)(BBl + sl * bbs);
            aB = MF(a2h, bh, aB); aB = MF(a2l, bh, aB); aB = MF(a2h, bl, aB);
            bh = *(const v8s*)(Bo + sl * bos); bl = *(const v8s*)(Bol + sl * bos);
            ao = MF(a2h, bh, ao); ao = MF(a2l, bh, ao); ao = MF(a2h, bl, ao);
        }

        // -------- exchange phase 1: (ai+ah), a1v, aA (+ ao col) --------
        if (kh == 0) {
            #pragma unroll
            for (int j = 0; j < 4; ++j) {
                const int row = g4 * 4 + j;
                scr[(0 * 4 + rt) * 256 + row * 16 + c] = ai[j] + ah[j];
                scr[(1 * 4 + rt) * 256 + row * 16 + c] = a1v[j];
                scr[(2 * 4 + rt) * 256 + row * 16 + c] = aA[j];
            }
            if (c == 0) {
                #pragma unroll
                for (int j = 0; j < 4; ++j) so[rt * 16 + g4 * 4 + j] = ao[j];
            }
        }
        __syncthreads();

        float s2v[4], zz2[4], s1v[4], rr1[4], AAv[4], xvv[4];
        if (kh == 1) {
            #pragma unroll
            for (int j = 0; j < 4; ++j) {
                const int row = g4 * 4 + j;
                const int b = bg * 64 + rt * 16 + row;
                const float AIAH = ai[j] + ah[j] + scr[(0 * 4 + rt) * 256 + row * 16 + c];
                const float A1v  = a1v[j] + scr[(1 * 4 + rt) * 256 + row * 16 + c];
                AAv[j] = aA[j] + scr[(2 * 4 + rt) * 256 + row * 16 + c];
                xvv[j] = (t + 1 < TT) ? xT[(size_t)(t + 1) * BATCH + b] : 0.f;
                s2v[j] = sigf(AIAH + b2rz);                 // r2 (c<8) / z2 (c>=8)
                s1v[j] = sigf(xvv[j] * wx1 + b1rz + A1v);   // r1 (c<8) / z1 (c>=8)
            }
            #pragma unroll
            for (int j = 0; j < 4; ++j) {
                zz2[j] = __shfl_xor(s2v[j], 8);
                rr1[j] = __shfl_xor(s1v[j], 8);
            }
        }
        __syncthreads();

        // -------- exchange phase 2: aB (reuses tile 0) --------
        if (kh == 0) {
            #pragma unroll
            for (int j = 0; j < 4; ++j) {
                const int row = g4 * 4 + j;
                scr[(0 * 4 + rt) * 256 + row * 16 + c] = aB[j];
            }
        }
        __syncthreads();

        if (kh == 1) {
            #pragma unroll
            for (int j = 0; j < 4; ++j) {
                const int row = g4 * 4 + j;
                const int b = bg * 64 + rt * 16 + row;
                if (c < 8) {
                    if (t < TT) {
                        const float ABv = aB[j] + scr[(0 * 4 + rt) * 256 + row * 16 + c];
                        float n2 = tanhf_(AAv[j] + bin2_ + s2v[j] * (ABv + bhn2_));
                        float hn = (1.f - zz2[j]) * n2 + zz2[j] * hprev[j];
                        hprev[j] = hn;
                        unsigned short hi = bf16_rne(hn), lo = bf16_rne(hn - bf16_f(hi));
                        GST2(h2wh + (size_t)b * HH + u, (unsigned)hi);
                        GST2(h2wl + (size_t)b * HH + u, (unsigned)lo);
                    }
                } else {
                    if (t + 1 < TT) {
                        float n1 = tanhf_(xvv[j] * wxn1 + bin1_ + rr1[j] * (AAv[j] + bhn1_));
                        float hn = (1.f - s1v[j]) * n1 + s1v[j] * hprev[j];
                        hprev[j] = hn;
                        unsigned short hi = bf16_rne(hn), lo = bf16_rne(hn - bf16_f(hi));
                        GST2(h1wh + (size_t)b * HH + u, (unsigned)hi);
                        GST2(h1wl + (size_t)b * HH + u, (unsigned)lo);
                    }
                }
                if (c == 0 && ug == 0 && t >= 1) {
                    float AO = ao[j] + so[rt * 16 + row];
                    out[(size_t)b * TT + (t - 1)] = AO + boutv;
                }
            }
        }
        ++ep;
        // fence (L1+L2 invalidate) only every INVP steps — ring guarantees no
        // address is re-read without >=1 fence since its previous-generation use.
        gridbar(barr, bg, ug, tid, ep, (t & invmask) == invmask);
    }
}

extern "C" void kernel_launch(void* const* d_in, const int* in_sizes, int n_in,
                              void* d_out, int out_size, void* d_ws, size_t ws_size,
                              hipStream_t stream) {
    const float* x    = (const float*)d_in[0];
    const float* Wih1 = (const float*)d_in[1];
    const float* Whh1 = (const float*)d_in[2];
    const float* bih1 = (const float*)d_in[3];
    const float* bhh1 = (const float*)d_in[4];
    const float* Wih2 = (const float*)d_in[5];
    const float* Whh2 = (const float*)d_in[6];
    const float* bih2 = (const float*)d_in[7];
    const float* bhh2 = (const float*)d_in[8];
    const float* Wout = (const float*)d_in[9];
    const float* bout = (const float*)d_in[10];
    float* outp = (float*)d_out;

    // ws layout: [ring: R MB][xT: 1 MB][barr: 8 KB]
    const size_t MB = 1048576;
    size_t avail = (ws_size > MB + 8192) ? ws_size - MB - 8192 : 2 * MB;
    int R = 2;
    while (R < 64 && (size_t)(R * 2) * MB <= avail) R *= 2;
    const int INVP = (R >= 4) ? (R / 2) : 1;   // fence period (power of 2)

    unsigned short* hws = (unsigned short*)d_ws;
    float* xT      = (float*)((char*)d_ws + (size_t)R * MB);
    unsigned* barr = (unsigned*)((char*)d_ws + (size_t)R * MB + MB);

    hipMemsetAsync((void*)barr, 0, 8192, stream);
    k_transpose<<<dim3(16, 4), 256, 0, stream>>>(x, xT);

    hipFuncSetAttribute((const void*)gru_mfma,
                        hipFuncAttributeMaxDynamicSharedMemorySize, LDS_BYTES);

    int rmask = R - 1, invmask = INVP - 1;
    void* args[] = { (void*)&xT,
                     (void*)&Wih1, (void*)&Whh1, (void*)&bih1, (void*)&bhh1,
                     (void*)&Wih2, (void*)&Whh2, (void*)&bih2, (void*)&bhh2,
                     (void*)&Wout, (void*)&bout,
                     (void*)&outp, (void*)&hws, (void*)&barr,
                     (void*)&rmask, (void*)&invmask };
    hipLaunchCooperativeKernel((void*)gru_mfma, dim3(NB), dim3(NT),
                               args, LDS_BYTES, stream);
}

// Round 8
// 11072.395 us; speedup vs baseline: 2.5750x; 1.0333x over previous
//
#include <hip/hip_runtime.h>

#define NB 256
#define NT 512
#define TT 1024
#define HH 512
#define BATCH 256

using v8s   = __attribute__((ext_vector_type(8))) short;
using f32x4 = __attribute__((ext_vector_type(4))) float;

// ---- LDS layout (bytes) ----
// Staging-time: dense panels at 0..131071. After the one-time VGPR hoist of
// Bi (O_RZ2I) and Bh (O_RZ2H), their regions are reused: exchange scratch at
// 0..20479 (inside old Bi) and `so` at 32768 (inside old Bh) — deliberate
// aliasing so the compiler cannot rematerialize the hoisted LDS reads.
#define O_RZ2I 0        // 32768: Wih2 r|z  bf16 hi+lo [s16][plane2][lane64][16B] -> VGPR
#define O_RZ2H 32768    // 32768: Whh2 r|z                                        -> VGPR
#define O_NA   65536    // 32768: [Wih2_n(8) | Whh1_n(8)]
#define O_RZ1  98304    // 32768: Whh1 r|z
#define O_NB   131072   // 16384: Whh2_n 8 cols compact [s16][plane2][slot32][16B]
#define O_WOUT 147456   // 2048:  Wout col hi+lo [s16][g4][16B]
#define O_ZERO 149504   // 16
#define LDS_BYTES 162064

#define SLOT_SH 524288  // shorts per ring slot: [h1h|h1l|h2h|h2l] x 131072

__device__ __forceinline__ float sigf(float v)   { return 1.f / (1.f + __expf(-v)); }
__device__ __forceinline__ float tanhf_(float v) { return 2.f / (1.f + __expf(-2.f * v)) - 1.f; }

__device__ __forceinline__ unsigned short bf16_rne(float f) {
    union { float f; unsigned u; } a; a.f = f;
    unsigned r = (a.u + 0x7fffu + ((a.u >> 16) & 1u)) >> 16;
    return (unsigned short)r;
}
__device__ __forceinline__ float bf16_f(unsigned short h) {
    union { unsigned u; float f; } a; a.u = ((unsigned)h) << 16; return a.f;
}
__device__ __forceinline__ f32x4 MF(v8s a, v8s b, f32x4 c) {
    return __builtin_amdgcn_mfma_f32_16x16x32_bf16(a, b, c, 0, 0, 0);
}

// write-through stores: h state reaches the chip coherence point before the
// barrier's vmcnt(0) drain + counter bump.
#define GST2(addr, val) \
    asm volatile("global_store_short %0, %1, off sc0 sc1" \
                 :: "v"(addr), "v"(val) : "memory");

// Flat per-bg barrier: one counter per bg; arrive with relaxed agent RMW,
// spin on the counter itself. Ring + periodic fence handle stale lines.
__device__ __forceinline__ void gridbar(unsigned* barr, int bg, int tid,
                                        unsigned ep, bool fence) {
    asm volatile("s_waitcnt vmcnt(0)" ::: "memory");
    __syncthreads();
    if (tid == 0) {
        unsigned* cnt = barr + bg * 64;
        __hip_atomic_fetch_add(cnt, 1u, __ATOMIC_RELAXED, __HIP_MEMORY_SCOPE_AGENT);
        while (__hip_atomic_load(cnt, __ATOMIC_RELAXED, __HIP_MEMORY_SCOPE_AGENT) < ep * 64u)
            __builtin_amdgcn_s_sleep(1);
        if (fence)
            __builtin_amdgcn_fence(__ATOMIC_ACQUIRE, "agent");
    }
    __syncthreads();
}

// x: [B][T] -> xT: [T][B]
__global__ __launch_bounds__(256) void k_transpose(const float* __restrict__ x,
                                                   float* __restrict__ xT) {
    __shared__ float tile[64][65];
    const int bt = blockIdx.x, bb = blockIdx.y;
    const int lt = threadIdx.x & 63, lb = threadIdx.x >> 6;
    #pragma unroll 4
    for (int i = 0; i < 16; ++i) {
        int row = lb + i * 4;
        tile[row][lt] = x[(size_t)(bb * 64 + row) * TT + bt * 64 + lt];
    }
    __syncthreads();
    #pragma unroll 4
    for (int i = 0; i < 16; ++i) {
        int row = lb + i * 4;
        xT[(size_t)(bt * 64 + row) * BATCH + bb * 64 + lt] = tile[lt][row];
    }
}

__global__ __launch_bounds__(NT, 1) void gru_mfma(
    const float* __restrict__ xT,
    const float* __restrict__ Wih1, const float* __restrict__ Whh1,
    const float* __restrict__ bih1, const float* __restrict__ bhh1,
    const float* __restrict__ Wih2, const float* __restrict__ Whh2,
    const float* __restrict__ bih2, const float* __restrict__ bhh2,
    const float* __restrict__ Wout, const float* __restrict__ bout,
    float* __restrict__ out,
    unsigned short* __restrict__ hws,
    unsigned* __restrict__ barr,
    int rmask, int invmask)
{
    extern __shared__ char lds_b[];
    const int tid = threadIdx.x, blk = blockIdx.x;
    const int bg = blk >> 6, ug = blk & 63;
    const int u0 = ug * 8;

    // ================= weight staging (bf16 hi+lo) — r5-verified =============
    for (int i = tid; i < 16 * 512; i += NT) {  // Wih2 r|z
        int n = i >> 9, k = i & 511;
        int row = (n < 8) ? (u0 + n) : (HH + u0 + (n - 8));
        float f = Wih2[(size_t)row * HH + k];
        unsigned short hi = bf16_rne(f), lo = bf16_rne(f - bf16_f(hi));
        int s = k >> 5, g = (k >> 3) & 3, j = k & 7, ln = g * 16 + n;
        int base = O_RZ2I + s * 2048 + ln * 16 + j * 2;
        *(unsigned short*)(lds_b + base) = hi;
        *(unsigned short*)(lds_b + base + 1024) = lo;
    }
    for (int i = tid; i < 16 * 512; i += NT) {  // Whh2 r|z
        int n = i >> 9, k = i & 511;
        int row = (n < 8) ? (u0 + n) : (HH + u0 + (n - 8));
        float f = Whh2[(size_t)row * HH + k];
        unsigned short hi = bf16_rne(f), lo = bf16_rne(f - bf16_f(hi));
        int s = k >> 5, g = (k >> 3) & 3, j = k & 7, ln = g * 16 + n;
        int base = O_RZ2H + s * 2048 + ln * 16 + j * 2;
        *(unsigned short*)(lds_b + base) = hi;
        *(unsigned short*)(lds_b + base + 1024) = lo;
    }
    for (int i = tid; i < 16 * 512; i += NT) {  // [Wih2_n | Whh1_n]
        int n = i >> 9, k = i & 511;
        float f = (n < 8) ? Wih2[(size_t)(2 * HH + u0 + n) * HH + k]
                          : Whh1[(size_t)(2 * HH + u0 + (n - 8)) * HH + k];
        unsigned short hi = bf16_rne(f), lo = bf16_rne(f - bf16_f(hi));
        int s = k >> 5, g = (k >> 3) & 3, j = k & 7, ln = g * 16 + n;
        int base = O_NA + s * 2048 + ln * 16 + j * 2;
        *(unsigned short*)(lds_b + base) = hi;
        *(unsigned short*)(lds_b + base + 1024) = lo;
    }
    for (int i = tid; i < 16 * 512; i += NT) {  // Whh1 r|z
        int n = i >> 9, k = i & 511;
        int row = (n < 8) ? (u0 + n) : (HH + u0 + (n - 8));
        float f = Whh1[(size_t)row * HH + k];
        unsigned short hi = bf16_rne(f), lo = bf16_rne(f - bf16_f(hi));
        int s = k >> 5, g = (k >> 3) & 3, j = k & 7, ln = g * 16 + n;
        int base = O_RZ1 + s * 2048 + ln * 16 + j * 2;
        *(unsigned short*)(lds_b + base) = hi;
        *(unsigned short*)(lds_b + base + 1024) = lo;
    }
    for (int i = tid; i < 8 * 512; i += NT) {   // Whh2_n compact 8 cols
        int c = i >> 9, k = i & 511;
        float f = Whh2[(size_t)(2 * HH + u0 + c) * HH + k];
        unsigned short hi = bf16_rne(f), lo = bf16_rne(f - bf16_f(hi));
        int s = k >> 5, g = (k >> 3) & 3, j = k & 7;
        int base = O_NB + s * 1024 + (g * 8 + c) * 16 + j * 2;
        *(unsigned short*)(lds_b + base) = hi;
        *(unsigned short*)(lds_b + base + 512) = lo;
    }
    for (int k = tid; k < 512; k += NT) {       // Wout col
        float f = Wout[k];
        unsigned short hi = bf16_rne(f), lo = bf16_rne(f - bf16_f(hi));
        int s = k >> 5, g = (k >> 3) & 3, j = k & 7;
        int base = O_WOUT + s * 64 + g * 16 + j * 2;
        *(unsigned short*)(lds_b + base) = hi;
        *(unsigned short*)(lds_b + base + 1024) = lo;
    }
    if (tid < 4) ((unsigned*)(lds_b + O_ZERO))[tid] = 0;

    // ====== h prologue into ring slot 0: h1(0), h2(-1)=0 (write-through) =====
    {
        const int rl = tid >> 3, uo = tid & 7;
        const int b = bg * 64 + rl, u = u0 + uo;
        unsigned short* s0 = hws;  // slot 0
        GST2(s0 + 262144 + (size_t)b * HH + u, 0u);   // h2 hi
        GST2(s0 + 393216 + (size_t)b * HH + u, 0u);   // h2 lo
        float x0 = xT[b];
        float r = sigf(x0 * Wih1[u] + bih1[u] + bhh1[u]);
        float z = sigf(x0 * Wih1[HH + u] + bih1[HH + u] + bhh1[HH + u]);
        float n = tanhf_(x0 * Wih1[2 * HH + u] + bih1[2 * HH + u] + r * bhh1[2 * HH + u]);
        float h = (1.f - z) * n;
        unsigned short hi = bf16_rne(h), lo = bf16_rne(h - bf16_f(hi));
        GST2(s0 + (size_t)b * HH + u, (unsigned)hi);           // h1 hi
        GST2(s0 + 131072 + (size_t)b * HH + u, (unsigned)lo);  // h1 lo
    }

    // ================= per-wave/lane constants (r5-verified) ==================
    const int w = tid >> 6, lane = tid & 63;
    const int n16 = lane & 15, g4 = lane >> 4;
    const int rt = w & 3, kh = w >> 2;       // row-tile(16 rows), k-half(256)
    const int c = n16, cu = c & 7;
    const int u = u0 + cu;
    const int sbase = kh * 8;

    float b2rz = 0, wx1 = 0, b1rz = 0, bin2_ = 0, bhn2_ = 0, wxn1 = 0, bin1_ = 0, bhn1_ = 0;
    float hprev[4] = {0.f, 0.f, 0.f, 0.f};
    if (kh == 1) {
        b2rz = (c < 8) ? bih2[u] + bhh2[u] : bih2[HH + u] + bhh2[HH + u];
        wx1  = (c < 8) ? Wih1[u] : Wih1[HH + u];
        b1rz = (c < 8) ? bih1[u] + bhh1[u] : bih1[HH + u] + bhh1[HH + u];
        bin2_ = bih2[2 * HH + u]; bhn2_ = bhh2[2 * HH + u];
        wxn1 = Wih1[2 * HH + u]; bin1_ = bih1[2 * HH + u]; bhn1_ = bhh1[2 * HH + u];
        if (c >= 8) {  // layer-1 lanes carry h1 in regs: init to h1(0)
            #pragma unroll
            for (int j = 0; j < 4; ++j) {
                int b = bg * 64 + rt * 16 + g4 * 4 + j;
                float x0 = xT[b];
                float r = sigf(x0 * Wih1[u] + bih1[u] + bhh1[u]);
                float z = sigf(x0 * Wih1[HH + u] + bih1[HH + u] + bhh1[HH + u]);
                float nn = tanhf_(x0 * Wih1[2 * HH + u] + bih1[2 * HH + u] + r * bhh1[2 * HH + u]);
                hprev[j] = (1.f - z) * nn;
            }
        }
    }
    const float boutv = bout[0];

    // B pointers for panels that STAY in LDS (incl. kh offsets — r4 bugfix)
    const char* BA = lds_b + O_NA   + lane * 16;
    const char* B1 = lds_b + O_RZ1  + lane * 16;
    const char* BBh = (n16 < 8) ? lds_b + O_NB + kh * 8192 + (g4 * 8 + n16) * 16
                                : lds_b + O_ZERO;
    const char* BBl = (n16 < 8) ? BBh + 512 : lds_b + O_ZERO;
    const int  bbs  = (n16 < 8) ? 1024 : 0;
    const char* Bo  = (n16 == 0) ? lds_b + O_WOUT + kh * 512 + g4 * 16 : lds_b + O_ZERO;
    const char* Bol = (n16 == 0) ? Bo + 1024 : lds_b + O_ZERO;
    const int  bos  = (n16 == 0) ? 64 : 0;

    // Exchange scratch: lives in the hoisted panels' dead LDS.
    // Row stride 20 words -> 4-row offset = 80 words = 16 mod 32 banks: <=2-way.
    float* scr = (float*)(lds_b + 0);        // 4 tiles x 4 rt x 16 rows x 20 w
    float* so  = (float*)(lds_b + 32768);    // 64 f32

    unsigned ep = 1;
    gridbar(barr, bg, tid, ep, true);  // fence once: kill replay-boundary staleness

    // ====== one-time hoist of Bi (Wih2 r|z) + Bh (Whh2 r|z) into VGPRs ======
    v8s RBi[8][2], RBh[8][2];
    {
        const char* Bi = lds_b + O_RZ2I + lane * 16;
        const char* Bh = lds_b + O_RZ2H + lane * 16;
        #pragma unroll
        for (int s8 = 0; s8 < 8; ++s8) {
            const int s = sbase + s8;
            RBi[s8][0] = *(const v8s*)(Bi + s * 2048);
            RBi[s8][1] = *(const v8s*)(Bi + s * 2048 + 1024);
            RBh[s8][0] = *(const v8s*)(Bh + s * 2048);
            RBh[s8][1] = *(const v8s*)(Bh + s * 2048 + 1024);
        }
    }
    __syncthreads();   // hoist complete before scr (aliasing bytes) is written

    // ================= main recurrence =================
    for (int t = 0; t <= TT; ++t) {
        const unsigned short* __restrict__ slotR = hws + (size_t)(t & rmask) * SLOT_SH;
        unsigned short* __restrict__ slotW = hws + (size_t)((t + 1) & rmask) * SLOT_SH;
        const unsigned short* __restrict__ h1rh = slotR;
        const unsigned short* __restrict__ h1rl = slotR + 131072;
        const unsigned short* __restrict__ h2rh = slotR + 262144;
        const unsigned short* __restrict__ h2rl = slotR + 393216;
        unsigned short* h1wh = slotW;
        unsigned short* h1wl = slotW + 131072;
        unsigned short* h2wh = slotW + 262144;
        unsigned short* h2wl = slotW + 393216;

        const size_t aoff = ((size_t)(bg * 64 + rt * 16 + n16) * HH + (size_t)kh * 256 + g4 * 8);
        const unsigned short* __restrict__ pa1h = h1rh + aoff;
        const unsigned short* __restrict__ pa1l = h1rl + aoff;
        const unsigned short* __restrict__ pa2h = h2rh + aoff;
        const unsigned short* __restrict__ pa2l = h2rl + aoff;

        f32x4 ai = {0.f,0.f,0.f,0.f}, ah = {0.f,0.f,0.f,0.f}, a1v = {0.f,0.f,0.f,0.f};
        f32x4 aA = {0.f,0.f,0.f,0.f}, aB = {0.f,0.f,0.f,0.f}, ao = {0.f,0.f,0.f,0.f};

        #pragma unroll
        for (int sl = 0; sl < 8; ++sl) {
            const int s = sbase + sl;
            const v8s a1h = *(const v8s*)(pa1h + sl * 32);  // normal cached loads
            const v8s a1l = *(const v8s*)(pa1l + sl * 32);
            const v8s a2h = *(const v8s*)(pa2h + sl * 32);
            const v8s a2l = *(const v8s*)(pa2l + sl * 32);
            ai = MF(a1h, RBi[sl][0], ai); ai = MF(a1l, RBi[sl][0], ai); ai = MF(a1h, RBi[sl][1], ai);
            ah = MF(a2h, RBh[sl][0], ah); ah = MF(a2l, RBh[sl][0], ah); ah = MF(a2h, RBh[sl][1], ah);
            v8s bh, bl;
            bh = *(const v8s*)(BA + s * 2048); bl = *(const v8s*)(BA + s * 2048 + 1024);
            aA = MF(a1h, bh, aA); aA = MF(a1l, bh, aA); aA = MF(a1h, bl, aA);
            bh = *(const v8s*)(B1 + s * 2048); bl = *(const v8s*)(B1 + s * 2048 + 1024);
            a1v = MF(a1h, bh, a1v); a1v = MF(a1l, bh, a1v); a1v = MF(a1h, bl, a1v);
            bh = *(const v8s*)(BBh + sl * bbs); bl = *(const v8s*)(BBl + sl * bbs);
            aB = MF(a2h, bh, aB); aB = MF(a2l, bh, aB); aB = MF(a2h, bl, aB);
            bh = *(const v8s*)(Bo + sl * bos); bl = *(const v8s*)(Bol + sl * bos);
            ao = MF(a2h, bh, ao); ao = MF(a2l, bh, ao); ao = MF(a2h, bl, ao);
        }

        // -------- single exchange phase: 4 tiles + ao col (conflict-free) ----
        if (kh == 0) {
            #pragma unroll
            for (int j = 0; j < 4; ++j) {
                const int row = g4 * 4 + j;
                scr[(0 * 4 + rt) * 320 + row * 20 + c] = ai[j] + ah[j];
                scr[(1 * 4 + rt) * 320 + row * 20 + c] = a1v[j];
                scr[(2 * 4 + rt) * 320 + row * 20 + c] = aA[j];
                scr[(3 * 4 + rt) * 320 + row * 20 + c] = aB[j];
            }
            if (c == 0) {
                #pragma unroll
                for (int j = 0; j < 4; ++j) so[rt * 16 + g4 * 4 + j] = ao[j];
            }
        }
        __syncthreads();

        if (kh == 1) {
            float s2v[4], zz2[4], s1v[4], rr1[4], AAv[4], ABv[4], xvv[4];
            #pragma unroll
            for (int j = 0; j < 4; ++j) {
                const int row = g4 * 4 + j;
                const int b = bg * 64 + rt * 16 + row;
                const float AIAH = ai[j] + ah[j] + scr[(0 * 4 + rt) * 320 + row * 20 + c];
                const float A1v  = a1v[j] + scr[(1 * 4 + rt) * 320 + row * 20 + c];
                AAv[j] = aA[j] + scr[(2 * 4 + rt) * 320 + row * 20 + c];
                ABv[j] = aB[j] + scr[(3 * 4 + rt) * 320 + row * 20 + c];
                xvv[j] = (t + 1 < TT) ? xT[(size_t)(t + 1) * BATCH + b] : 0.f;
                s2v[j] = sigf(AIAH + b2rz);                 // r2 (c<8) / z2 (c>=8)
                s1v[j] = sigf(xvv[j] * wx1 + b1rz + A1v);   // r1 (c<8) / z1 (c>=8)
            }
            #pragma unroll
            for (int j = 0; j < 4; ++j) {
                zz2[j] = __shfl_xor(s2v[j], 8);
                rr1[j] = __shfl_xor(s1v[j], 8);
            }
            #pragma unroll
            for (int j = 0; j < 4; ++j) {
                const int row = g4 * 4 + j;
                const int b = bg * 64 + rt * 16 + row;
                if (c < 8) {
                    if (t < TT) {
                        float n2 = tanhf_(AAv[j] + bin2_ + s2v[j] * (ABv[j] + bhn2_));
                        float hn = (1.f - zz2[j]) * n2 + zz2[j] * hprev[j];
                        hprev[j] = hn;
                        unsigned short hi = bf16_rne(hn), lo = bf16_rne(hn - bf16_f(hi));
                        GST2(h2wh + (size_t)b * HH + u, (unsigned)hi);
                        GST2(h2wl + (size_t)b * HH + u, (unsigned)lo);
                    }
                } else {
                    if (t + 1 < TT) {
                        float n1 = tanhf_(xvv[j] * wxn1 + bin1_ + rr1[j] * (AAv[j] + bhn1_));
                        float hn = (1.f - s1v[j]) * n1 + s1v[j] * hprev[j];
                        hprev[j] = hn;
                        unsigned short hi = bf16_rne(hn), lo = bf16_rne(hn - bf16_f(hi));
                        GST2(h1wh + (size_t)b * HH + u, (unsigned)hi);
                        GST2(h1wl + (size_t)b * HH + u, (unsigned)lo);
                    }
                }
                if (c == 0 && ug == 0 && t >= 1) {
                    float AO = ao[j] + so[rt * 16 + row];
                    out[(size_t)b * TT + (t - 1)] = AO + boutv;
                }
            }
        }
        ++ep;
        gridbar(barr, bg, tid, ep, (t & invmask) == invmask);
    }
}

extern "C" void kernel_launch(void* const* d_in, const int* in_sizes, int n_in,
                              void* d_out, int out_size, void* d_ws, size_t ws_size,
                              hipStream_t stream) {
    const float* x    = (const float*)d_in[0];
    const float* Wih1 = (const float*)d_in[1];
    const float* Whh1 = (const float*)d_in[2];
    const float* bih1 = (const float*)d_in[3];
    const float* bhh1 = (const float*)d_in[4];
    const float* Wih2 = (const float*)d_in[5];
    const float* Whh2 = (const float*)d_in[6];
    const float* bih2 = (const float*)d_in[7];
    const float* bhh2 = (const float*)d_in[8];
    const float* Wout = (const float*)d_in[9];
    const float* bout = (const float*)d_in[10];
    float* outp = (float*)d_out;

    // ws layout: [ring: R MB][xT: 1 MB][barr: 8 KB]
    const size_t MB = 1048576;
    size_t avail = (ws_size > MB + 8192) ? ws_size - MB - 8192 : 2 * MB;
    int R = 2;
    while (R < 64 && (size_t)(R * 2) * MB <= avail) R *= 2;
    const int INVP = (R >= 4) ? (R / 2) : 1;

    unsigned short* hws = (unsigned short*)d_ws;
    float* xT      = (float*)((char*)d_ws + (size_t)R * MB);
    unsigned* barr = (unsigned*)((char*)d_ws + (size_t)R * MB + MB);

    hipMemsetAsync((void*)barr, 0, 8192, stream);
    k_transpose<<<dim3(16, 4), 256, 0, stream>>>(x, xT);

    hipFuncSetAttribute((const void*)gru_mfma,
                        hipFuncAttributeMaxDynamicSharedMemorySize, LDS_BYTES);

    int rmask = R - 1, invmask = INVP - 1;
    void* args[] = { (void*)&xT,
                     (void*)&Wih1, (void*)&Whh1, (void*)&bih1, (void*)&bhh1,
                     (void*)&Wih2, (void*)&Whh2, (void*)&bih2, (void*)&bhh2,
                     (void*)&Wout, (void*)&bout,
                     (void*)&outp, (void*)&hws, (void*)&barr,
                     (void*)&rmask, (void*)&invmask };
    hipLaunchCooperativeKernel((void*)gru_mfma, dim3(NB), dim3(NT),
                               args, LDS_BYTES, stream);
}